// Round 2
// baseline (495.998 us; speedup 1.0000x reference)
//
#include <hip/hip_runtime.h>
#include <hip/hip_bf16.h>
#include <math.h>

// Problem constants (fixed dataset: n=100, k=5, q=75, d=4096)
#define NQUERY 7500
#define NCLS   100
#define DIM    4096
#define KQ     75
#define KSUP   5
#define RPC    80        // rows per class in x = k+q
#define MPAD   7552      // 59 * 128
#define NPAD   112       // 7 * 16
#define CAPQ   1024      // max queries per class list
#define RCAP   4096      // max refine entries
#define EPSF   1e-8f
#define KSPLIT 16        // k-splits for both GEMMs (K=256 per block)
#define KCHUNK 256
#define KS_IT  8         // KCHUNK/32

typedef __attribute__((ext_vector_type(8))) short bf16x8;
typedef __attribute__((ext_vector_type(4))) float f32x4;

__device__ __forceinline__ int xrow_of_query(int j) {
    return (j / KQ) * RPC + KSUP + (j % KQ);
}
__device__ __forceinline__ short bf16t(float x) {       // truncate fp32 -> bf16 bits
    union { float f; unsigned u; } v; v.f = x;
    return (short)(v.u >> 16);
}
__device__ __forceinline__ float bf16hi(float x) {      // fp32 with low mantissa cleared
    union { float f; unsigned u; } v; v.f = x;
    v.u &= 0xFFFF0000u; return v.f;
}

// ---------------- K1a: proto chunk + partial norm2  (grid: NCLS x 4 chunks)
__global__ __launch_bounds__(256) void k_proto1(const float* __restrict__ x,
        float* __restrict__ proto, float* __restrict__ norm2) {
    const int c = blockIdx.x, ch = blockIdx.y, t = threadIdx.x;
    const int i = ch * 1024 + t * 4;
    const float* b0 = x + (size_t)(c * RPC) * DIM;
    f32x4 s = {0.f, 0.f, 0.f, 0.f};
#pragma unroll
    for (int r = 0; r < KSUP; ++r)
        s += *(const f32x4*)(b0 + (size_t)r * DIM + i);
    s = s / 5.0f;
    *(f32x4*)(proto + (size_t)c*DIM + i) = s;
    float ssq = s[0]*s[0] + s[1]*s[1] + s[2]*s[2] + s[3]*s[3];
    for (int o = 32; o; o >>= 1) ssq += __shfl_down(ssq, o);
    if ((t & 63) == 0) atomicAdd(&norm2[c], ssq);
}

// ---------------- K1b: normalize -> Phi/Plo bf16 split, es  (grid: NPAD x 4)
__global__ __launch_bounds__(256) void k_proto2(const float* __restrict__ proto,
        const float* __restrict__ norm2, short* __restrict__ Phi, short* __restrict__ Plo,
        float* __restrict__ es) {
    const int c = blockIdx.x, ch = blockIdx.y, t = threadIdx.x;
    const int i = ch * 1024 + t * 4;
    if (c >= NCLS) {
#pragma unroll
        for (int e = 0; e < 4; ++e) { Phi[(size_t)c*DIM+i+e] = 0; Plo[(size_t)c*DIM+i+e] = 0; }
        return;
    }
    const float tot = norm2[c];
    const float inv = 1.f / fmaxf(sqrtf(tot), EPSF);
    if (ch == 0 && t == 0) es[c] = expf(tot * inv * inv);
    f32x4 pv = *(const f32x4*)(proto + (size_t)c*DIM + i);
#pragma unroll
    for (int e = 0; e < 4; ++e) {
        float pn = pv[e] * inv;
        float hh = bf16hi(pn);
        Phi[(size_t)c*DIM + i + e] = bf16t(pn);
        Plo[(size_t)c*DIM + i + e] = bf16t(pn - hh);
    }
}

// ---------------- K2: GEMM1  S[j,c] += q_j . pn_c  (3-term bf16 split), also nq2[j] += |q_j|^2
// grid (59 m-blocks, KSPLIT), block 256: 4 waves x (2 m-tiles x 7 n-tiles)
__global__ __launch_bounds__(256) void k_gemm1(const float* __restrict__ x,
        const short* __restrict__ Phi, const short* __restrict__ Plo,
        float* __restrict__ S, float* __restrict__ nq2) {
    const int bx = blockIdx.x, kz = blockIdx.y;
    const int w = threadIdx.x >> 6, lane = threadIdx.x & 63;
    const int lm = lane & 15, kq = lane >> 4;
    const int m0 = bx * 128 + w * 32;

    const float* pa[2];
    int jr[2];
    float ssq[2] = {0.f, 0.f};
#pragma unroll
    for (int mt = 0; mt < 2; ++mt) {
        int j = m0 + mt * 16 + lm;
        jr[mt] = j;
        int jc = j < NQUERY ? j : NQUERY - 1;
        pa[mt] = x + (size_t)xrow_of_query(jc) * DIM + kz * KCHUNK + kq * 8;
    }
    const short* pbh = Phi + (size_t)lm * DIM + kz * KCHUNK + kq * 8;
    const short* pbl = Plo + (size_t)lm * DIM + kz * KCHUNK + kq * 8;

    f32x4 acc[2][7];
#pragma unroll
    for (int mt = 0; mt < 2; ++mt)
#pragma unroll
        for (int nt = 0; nt < 7; ++nt) acc[mt][nt] = (f32x4){0.f,0.f,0.f,0.f};

    for (int ks = 0; ks < KS_IT; ++ks) {
        const int ko = ks * 32;
        bf16x8 ah[2], al[2];
#pragma unroll
        for (int mt = 0; mt < 2; ++mt) {
            f32x4 f0 = *(const f32x4*)(pa[mt] + ko);
            f32x4 f1 = *(const f32x4*)(pa[mt] + ko + 4);
            float fv[8] = {f0[0],f0[1],f0[2],f0[3],f1[0],f1[1],f1[2],f1[3]};
            bf16x8 h, l;
#pragma unroll
            for (int e = 0; e < 8; ++e) {
                float xx = fv[e];
                ssq[mt] += xx * xx;
                float hh = bf16hi(xx);
                h[e] = bf16t(xx);
                l[e] = bf16t(xx - hh);
            }
            ah[mt] = h; al[mt] = l;
        }
        bf16x8 bh[7], bl[7];
#pragma unroll
        for (int nt = 0; nt < 7; ++nt) {
            bh[nt] = *(const bf16x8*)(pbh + (size_t)nt * 16 * DIM + ko);
            bl[nt] = *(const bf16x8*)(pbl + (size_t)nt * 16 * DIM + ko);
        }
#pragma unroll
        for (int mt = 0; mt < 2; ++mt)
#pragma unroll
            for (int nt = 0; nt < 7; ++nt) {
                acc[mt][nt] = __builtin_amdgcn_mfma_f32_16x16x32_bf16(ah[mt], bh[nt], acc[mt][nt], 0, 0, 0);
                acc[mt][nt] = __builtin_amdgcn_mfma_f32_16x16x32_bf16(ah[mt], bl[nt], acc[mt][nt], 0, 0, 0);
                acc[mt][nt] = __builtin_amdgcn_mfma_f32_16x16x32_bf16(al[mt], bh[nt], acc[mt][nt], 0, 0, 0);
            }
    }
#pragma unroll
    for (int mt = 0; mt < 2; ++mt) {
        float s2 = ssq[mt];
        s2 += __shfl_xor(s2, 16);
        s2 += __shfl_xor(s2, 32);
        if (kq == 0 && jr[mt] < NQUERY) atomicAdd(&nq2[jr[mt]], s2);
    }
#pragma unroll
    for (int mt = 0; mt < 2; ++mt)
#pragma unroll
        for (int nt = 0; nt < 7; ++nt)
#pragma unroll
            for (int r = 0; r < 4; ++r) {
                int j = m0 + mt * 16 + kq * 4 + r;
                int c = nt * 16 + lm;
                atomicAdd(&S[(size_t)j * NPAD + c], acc[mt][nt][r]);
            }
}

// ---------------- K3: per-query argmax/top2, invq, coef, refine-list
__global__ __launch_bounds__(256) void k_argmax(const float* __restrict__ S,
        const float* __restrict__ nq2, int* __restrict__ label, float* __restrict__ coef,
        float* __restrict__ invq, int* __restrict__ rcnt, int* __restrict__ rlist) {
    const int j = blockIdx.x * 256 + threadIdx.x;
    if (j >= NQUERY) return;
    const float* row = S + (size_t)j * NPAD;
    float m1 = -1e30f, m2 = -1e30f;
    int i1 = 0, i2 = 0;
    for (int c = 0; c < NCLS; ++c) {
        float v = row[c];
        if (v > m1) { m2 = m1; i2 = i1; m1 = v; i1 = c; }
        else if (v > m2) { m2 = v; i2 = c; }
    }
    const float inv = 1.f / fmaxf(sqrtf(nq2[j]), EPSF);
    invq[j] = inv;
    label[j] = i1;
    coef[j] = expf(m1 * inv);
    if ((m1 - m2) * inv < 1e-4f) {
        int p = atomicAdd(rcnt, 1);
        if (p < RCAP) rlist[p] = j | (i1 << 13) | (i2 << 20);
    }
}

// ---------------- K4: fp64 refinement of borderline argmax decisions (1 wave/block, 512 blocks)
__global__ __launch_bounds__(64) void k_refine(const float* __restrict__ x,
        const float* __restrict__ S, const float* __restrict__ invq,
        int* __restrict__ label, float* __restrict__ coef,
        const int* __restrict__ rcnt, const int* __restrict__ rlist) {
    const int cnt = min(*rcnt, RCAP);
    const int lane = threadIdx.x;
    for (int e = blockIdx.x; e < cnt; e += gridDim.x) {
        const int pk = rlist[e];
        const int j = pk & 8191, c1 = (pk >> 13) & 127, c2 = (pk >> 20) & 127;
        const float* xq = x + (size_t)xrow_of_query(j) * DIM;
        const int cc[2] = {c1, c2};
        double cosv[2];
#pragma unroll
        for (int s = 0; s < 2; ++s) {
            const float* xb = x + (size_t)(cc[s] * RPC) * DIM;
            double dt = 0.0, pp = 0.0, q2 = 0.0;
            for (int i = lane; i < DIM; i += 64) {
                double p = (double)xb[i] + (double)xb[i + DIM] + (double)xb[i + 2*DIM]
                         + (double)xb[i + 3*DIM] + (double)xb[i + 4*DIM];
                double qv = (double)xq[i];
                dt += p * qv; pp += p * p; q2 += qv * qv;
            }
            for (int o = 32; o; o >>= 1) {
                dt += __shfl_down(dt, o);
                pp += __shfl_down(pp, o);
                q2 += __shfl_down(q2, o);
            }
            cosv[s] = dt / (sqrt(pp) * sqrt(q2));   // /5 on proto cancels in cosine
        }
        if (lane == 0) {
            int win = (cosv[1] > cosv[0] || (cosv[1] == cosv[0] && c2 < c1)) ? c2 : c1;
            if (win != c1) {
                label[j] = win;
                coef[j] = expf(S[(size_t)j * NPAD + win] * invq[j]);
            }
        }
    }
}

// ---------------- K5: build per-class query lists
__global__ __launch_bounds__(256) void k_lists(const int* __restrict__ label,
        int* __restrict__ cls_cnt, int* __restrict__ cls_list) {
    const int j = blockIdx.x * 256 + threadIdx.x;
    if (j >= NQUERY) return;
    const int c = label[j];
    const int p = atomicAdd(&cls_cnt[c], 1);
    if (p < CAPQ) cls_list[c * CAPQ + p] = j;
}

// ---------------- K6: adapted-proto scatter sum: AP[c] += sum coef[j]*x[q_j]  (unnormalized)
__global__ __launch_bounds__(128) void k_adapt(const float* __restrict__ x,
        const float* __restrict__ coef, const int* __restrict__ cls_cnt,
        const int* __restrict__ cls_list, float* __restrict__ AP) {
    const int cx = blockIdx.x, c = blockIdx.y, sl = blockIdx.z;
    const int i0 = cx * 512 + threadIdx.x * 4;
    const int n = min(cls_cnt[c], CAPQ);
    f32x4 acc = {0.f, 0.f, 0.f, 0.f};
    for (int e = sl; e < n; e += 4) {
        const int j = cls_list[c * CAPQ + e];
        const float cf = coef[j];
        const f32x4 v = *(const f32x4*)(x + (size_t)xrow_of_query(j) * DIM + i0);
        acc += v * cf;
    }
    float* dst = AP + (size_t)c * DIM + i0;
    atomicAdd(dst + 0, acc[0]);
    atomicAdd(dst + 1, acc[1]);
    atomicAdd(dst + 2, acc[2]);
    atomicAdd(dst + 3, acc[3]);
}

// ---------------- K7a: AP += es*proto, partial norm2b  (grid: NCLS x 4)
__global__ __launch_bounds__(256) void k_ap1(float* __restrict__ AP,
        const float* __restrict__ proto, const float* __restrict__ es,
        float* __restrict__ norm2b) {
    const int c = blockIdx.x, ch = blockIdx.y, t = threadIdx.x;
    const int i = ch * 1024 + t * 4;
    const float e = es[c];
    f32x4 a = *(const f32x4*)(AP + (size_t)c*DIM + i);
    f32x4 pr = *(const f32x4*)(proto + (size_t)c*DIM + i);
    f32x4 s = a + pr * e;
    *(f32x4*)(AP + (size_t)c*DIM + i) = s;
    float ssq = s[0]*s[0] + s[1]*s[1] + s[2]*s[2] + s[3]*s[3];
    for (int o = 32; o; o >>= 1) ssq += __shfl_down(ssq, o);
    if ((t & 63) == 0) atomicAdd(&norm2b[c], ssq);
}

// ---------------- K7b: normalize AP -> APhi bf16 (padded rows zero)  (grid: NPAD x 4)
__global__ __launch_bounds__(256) void k_ap2(const float* __restrict__ AP,
        const float* __restrict__ norm2b, short* __restrict__ APhi) {
    const int c = blockIdx.x, ch = blockIdx.y, t = threadIdx.x;
    const int i = ch * 1024 + t * 4;
    if (c >= NCLS) {
#pragma unroll
        for (int e = 0; e < 4; ++e) APhi[(size_t)c*DIM + i + e] = 0;
        return;
    }
    const float inv = 1.f / fmaxf(sqrtf(norm2b[c]), EPSF);
    f32x4 a = *(const f32x4*)(AP + (size_t)c*DIM + i);
#pragma unroll
    for (int e = 0; e < 4; ++e) APhi[(size_t)c*DIM + i + e] = bf16t(a[e] * inv);
}

// ---------------- K8: GEMM2  out[j,c] += tao * invq[j] * (qhi_j . apn_c)
__global__ __launch_bounds__(256) void k_gemm2(const float* __restrict__ x,
        const short* __restrict__ APhi, const float* __restrict__ invq,
        const float* __restrict__ tao, float* __restrict__ out) {
    const int bx = blockIdx.x, kz = blockIdx.y;
    const int w = threadIdx.x >> 6, lane = threadIdx.x & 63;
    const int lm = lane & 15, kq = lane >> 4;
    const int m0 = bx * 128 + w * 32;

    const float* pa[2];
#pragma unroll
    for (int mt = 0; mt < 2; ++mt) {
        int j = m0 + mt * 16 + lm;
        int jc = j < NQUERY ? j : NQUERY - 1;
        pa[mt] = x + (size_t)xrow_of_query(jc) * DIM + kz * KCHUNK + kq * 8;
    }
    const short* pb = APhi + (size_t)lm * DIM + kz * KCHUNK + kq * 8;

    f32x4 acc[2][7];
#pragma unroll
    for (int mt = 0; mt < 2; ++mt)
#pragma unroll
        for (int nt = 0; nt < 7; ++nt) acc[mt][nt] = (f32x4){0.f,0.f,0.f,0.f};

    for (int ks = 0; ks < KS_IT; ++ks) {
        const int ko = ks * 32;
        bf16x8 ah[2];
#pragma unroll
        for (int mt = 0; mt < 2; ++mt) {
            f32x4 f0 = *(const f32x4*)(pa[mt] + ko);
            f32x4 f1 = *(const f32x4*)(pa[mt] + ko + 4);
            float fv[8] = {f0[0],f0[1],f0[2],f0[3],f1[0],f1[1],f1[2],f1[3]};
            bf16x8 h;
#pragma unroll
            for (int e = 0; e < 8; ++e) h[e] = bf16t(fv[e]);
            ah[mt] = h;
        }
        bf16x8 bh[7];
#pragma unroll
        for (int nt = 0; nt < 7; ++nt)
            bh[nt] = *(const bf16x8*)(pb + (size_t)nt * 16 * DIM + ko);
#pragma unroll
        for (int mt = 0; mt < 2; ++mt)
#pragma unroll
            for (int nt = 0; nt < 7; ++nt)
                acc[mt][nt] = __builtin_amdgcn_mfma_f32_16x16x32_bf16(ah[mt], bh[nt], acc[mt][nt], 0, 0, 0);
    }
    const float tv = tao[0];
#pragma unroll
    for (int mt = 0; mt < 2; ++mt)
#pragma unroll
        for (int nt = 0; nt < 7; ++nt)
#pragma unroll
            for (int r = 0; r < 4; ++r) {
                int j = m0 + mt * 16 + kq * 4 + r;
                int c = nt * 16 + lm;
                if (j < NQUERY && c < NCLS)
                    atomicAdd(&out[(size_t)j * NCLS + c], tv * invq[j] * acc[mt][nt][r]);
            }
}

// ---------------- workspace layout (bytes)
#define OFF_S      0u
#define OFF_NQ2    3383296u
#define OFF_CCNT   3413504u
#define OFF_RCNT   3413952u
#define OFF_N2     3414016u
#define OFF_N2B    3414528u
#define OFF_AP     3415040u
#define ZERO_BYTES 5053440u          // S..AP inclusive
#define OFF_PROTO  5053440u
#define OFF_PHI    6691840u
#define OFF_PLO    7609344u
#define OFF_ES     8526848u
#define OFF_LABEL  8527360u
#define OFF_COEF   8557568u
#define OFF_INVQ   8587776u
#define OFF_RLIST  8617984u
#define OFF_CLIST  8634368u
#define OFF_APHI   9043968u

extern "C" void kernel_launch(void* const* d_in, const int* in_sizes, int n_in,
                              void* d_out, int out_size, void* d_ws, size_t ws_size,
                              hipStream_t stream) {
    const float* x   = (const float*)d_in[0];
    const float* tao = (const float*)d_in[1];
    char* ws = (char*)d_ws;

    float* S       = (float*)(ws + OFF_S);
    float* nq2     = (float*)(ws + OFF_NQ2);
    int*   ccnt    = (int*)  (ws + OFF_CCNT);
    int*   rcnt    = (int*)  (ws + OFF_RCNT);
    float* norm2   = (float*)(ws + OFF_N2);
    float* norm2b  = (float*)(ws + OFF_N2B);
    float* AP      = (float*)(ws + OFF_AP);
    float* proto   = (float*)(ws + OFF_PROTO);
    short* Phi     = (short*)(ws + OFF_PHI);
    short* Plo     = (short*)(ws + OFF_PLO);
    float* es      = (float*)(ws + OFF_ES);
    int*   label   = (int*)  (ws + OFF_LABEL);
    float* coef    = (float*)(ws + OFF_COEF);
    float* invq    = (float*)(ws + OFF_INVQ);
    int*   rlist   = (int*)  (ws + OFF_RLIST);
    int*   clist   = (int*)  (ws + OFF_CLIST);
    short* APhi    = (short*)(ws + OFF_APHI);

    hipMemsetAsync(ws, 0, ZERO_BYTES, stream);
    hipMemsetAsync(d_out, 0, (size_t)out_size * sizeof(float), stream);

    k_proto1<<<dim3(NCLS, 4), 256, 0, stream>>>(x, proto, norm2);
    k_proto2<<<dim3(NPAD, 4), 256, 0, stream>>>(proto, norm2, Phi, Plo, es);
    k_gemm1 <<<dim3(59, KSPLIT), 256, 0, stream>>>(x, Phi, Plo, S, nq2);
    k_argmax<<<30, 256, 0, stream>>>(S, nq2, label, coef, invq, rcnt, rlist);
    k_refine<<<512, 64, 0, stream>>>(x, S, invq, label, coef, rcnt, rlist);
    k_lists <<<30, 256, 0, stream>>>(label, ccnt, clist);
    k_adapt <<<dim3(8, NCLS, 4), 128, 0, stream>>>(x, coef, ccnt, clist, AP);
    k_ap1   <<<dim3(NCLS, 4), 256, 0, stream>>>(AP, proto, es, norm2b);
    k_ap2   <<<dim3(NPAD, 4), 256, 0, stream>>>(AP, norm2b, APhi);
    k_gemm2 <<<dim3(59, KSPLIT), 256, 0, stream>>>(x, APhi, invq, tao, (float*)d_out);
}

// Round 3
// 419.756 us; speedup vs baseline: 1.1816x; 1.1816x over previous
//
#include <hip/hip_runtime.h>
#include <hip/hip_bf16.h>
#include <math.h>

// Problem constants (fixed dataset: n=100, k=5, q=75, d=4096)
#define NQUERY 7500
#define NCLS   100
#define DIM    4096
#define KQ     75
#define KSUP   5
#define RPC    80        // rows per class in x = k+q
#define MPAD   7552      // 59 * 128
#define NPAD   112       // 7 * 16
#define CAPQ   256       // max queries per class list (binomial(7500,0.01) max ~110)
#define RCAP   2048      // max refine entries
#define EPSF   1e-8f
#define SELEM  845824    // MPAD * NPAD elements per partial slice
#define SLICE_BYTES 3383296u

typedef __attribute__((ext_vector_type(8))) short bf16x8;
typedef __attribute__((ext_vector_type(4))) float f32x4;

__device__ __forceinline__ int xrow_of_query(int j) {
    return (j / KQ) * RPC + KSUP + (j % KQ);
}
__device__ __forceinline__ short bf16t(float x) {       // truncate fp32 -> bf16 bits
    union { float f; unsigned u; } v; v.f = x;
    return (short)(v.u >> 16);
}
__device__ __forceinline__ float bf16hi(float x) {      // fp32 with low mantissa cleared
    union { float f; unsigned u; } v; v.f = x;
    v.u &= 0xFFFF0000u; return v.f;
}

// ---------------- K1a: proto chunk + partial norm2  (grid: NCLS x 4 chunks)
__global__ __launch_bounds__(256) void k_proto1(const float* __restrict__ x,
        float* __restrict__ proto, float* __restrict__ norm2) {
    const int c = blockIdx.x, ch = blockIdx.y, t = threadIdx.x;
    const int i = ch * 1024 + t * 4;
    const float* b0 = x + (size_t)(c * RPC) * DIM;
    f32x4 s = {0.f, 0.f, 0.f, 0.f};
#pragma unroll
    for (int r = 0; r < KSUP; ++r)
        s += *(const f32x4*)(b0 + (size_t)r * DIM + i);
    s = s / 5.0f;
    *(f32x4*)(proto + (size_t)c*DIM + i) = s;
    float ssq = s[0]*s[0] + s[1]*s[1] + s[2]*s[2] + s[3]*s[3];
    for (int o = 32; o; o >>= 1) ssq += __shfl_down(ssq, o);
    if ((t & 63) == 0) atomicAdd(&norm2[c], ssq);
}

// ---------------- K1b: normalize -> Phi/Plo bf16 split, es  (grid: NPAD x 4)
__global__ __launch_bounds__(256) void k_proto2(const float* __restrict__ proto,
        const float* __restrict__ norm2, short* __restrict__ Phi, short* __restrict__ Plo,
        float* __restrict__ es) {
    const int c = blockIdx.x, ch = blockIdx.y, t = threadIdx.x;
    const int i = ch * 1024 + t * 4;
    if (c >= NCLS) {
#pragma unroll
        for (int e = 0; e < 4; ++e) { Phi[(size_t)c*DIM+i+e] = 0; Plo[(size_t)c*DIM+i+e] = 0; }
        return;
    }
    const float tot = norm2[c];
    const float inv = 1.f / fmaxf(sqrtf(tot), EPSF);
    if (ch == 0 && t == 0) es[c] = expf(tot * inv * inv);
    f32x4 pv = *(const f32x4*)(proto + (size_t)c*DIM + i);
#pragma unroll
    for (int e = 0; e < 4; ++e) {
        float pn = pv[e] * inv;
        float hh = bf16hi(pn);
        Phi[(size_t)c*DIM + i + e] = bf16t(pn);
        Plo[(size_t)c*DIM + i + e] = bf16t(pn - hh);
    }
}

// ---------------- K2: GEMM1 partials  Spart[kz][j,c] = q_j . pn_c  (3-term bf16 split)
__global__ __launch_bounds__(256) void k_gemm1(const float* __restrict__ x,
        const short* __restrict__ Phi, const short* __restrict__ Plo,
        float* __restrict__ Spart, float* __restrict__ nq2) {
    const int bx = blockIdx.x, kz = blockIdx.y, nks = gridDim.y;
    const int kchunk = DIM / nks, nit = kchunk / 32;
    const int w = threadIdx.x >> 6, lane = threadIdx.x & 63;
    const int lm = lane & 15, kq = lane >> 4;
    const int m0 = bx * 128 + w * 32;

    const float* pa[2];
    int jr[2];
    float ssq[2] = {0.f, 0.f};
#pragma unroll
    for (int mt = 0; mt < 2; ++mt) {
        int j = m0 + mt * 16 + lm;
        jr[mt] = j;
        int jc = j < NQUERY ? j : NQUERY - 1;
        pa[mt] = x + (size_t)xrow_of_query(jc) * DIM + kz * kchunk + kq * 8;
    }
    const short* pbh = Phi + (size_t)lm * DIM + kz * kchunk + kq * 8;
    const short* pbl = Plo + (size_t)lm * DIM + kz * kchunk + kq * 8;

    f32x4 acc[2][7];
#pragma unroll
    for (int mt = 0; mt < 2; ++mt)
#pragma unroll
        for (int nt = 0; nt < 7; ++nt) acc[mt][nt] = (f32x4){0.f,0.f,0.f,0.f};

    for (int ks = 0; ks < nit; ++ks) {
        const int ko = ks * 32;
        bf16x8 ah[2], al[2];
#pragma unroll
        for (int mt = 0; mt < 2; ++mt) {
            f32x4 f0 = *(const f32x4*)(pa[mt] + ko);
            f32x4 f1 = *(const f32x4*)(pa[mt] + ko + 4);
            float fv[8] = {f0[0],f0[1],f0[2],f0[3],f1[0],f1[1],f1[2],f1[3]};
            bf16x8 h, l;
#pragma unroll
            for (int e = 0; e < 8; ++e) {
                float xx = fv[e];
                ssq[mt] += xx * xx;
                float hh = bf16hi(xx);
                h[e] = bf16t(xx);
                l[e] = bf16t(xx - hh);
            }
            ah[mt] = h; al[mt] = l;
        }
        bf16x8 bh[7], bl[7];
#pragma unroll
        for (int nt = 0; nt < 7; ++nt) {
            bh[nt] = *(const bf16x8*)(pbh + (size_t)nt * 16 * DIM + ko);
            bl[nt] = *(const bf16x8*)(pbl + (size_t)nt * 16 * DIM + ko);
        }
#pragma unroll
        for (int mt = 0; mt < 2; ++mt)
#pragma unroll
            for (int nt = 0; nt < 7; ++nt) {
                acc[mt][nt] = __builtin_amdgcn_mfma_f32_16x16x32_bf16(ah[mt], bh[nt], acc[mt][nt], 0, 0, 0);
                acc[mt][nt] = __builtin_amdgcn_mfma_f32_16x16x32_bf16(ah[mt], bl[nt], acc[mt][nt], 0, 0, 0);
                acc[mt][nt] = __builtin_amdgcn_mfma_f32_16x16x32_bf16(al[mt], bh[nt], acc[mt][nt], 0, 0, 0);
            }
    }
#pragma unroll
    for (int mt = 0; mt < 2; ++mt) {
        float s2 = ssq[mt];
        s2 += __shfl_xor(s2, 16);
        s2 += __shfl_xor(s2, 32);
        if (kq == 0 && jr[mt] < NQUERY) atomicAdd(&nq2[jr[mt]], s2);
    }
    float* sp = Spart + (size_t)kz * SELEM;
#pragma unroll
    for (int mt = 0; mt < 2; ++mt)
#pragma unroll
        for (int nt = 0; nt < 7; ++nt)
#pragma unroll
            for (int r = 0; r < 4; ++r) {
                int j = m0 + mt * 16 + kq * 4 + r;
                int c = nt * 16 + lm;
                sp[(size_t)j * NPAD + c] = acc[mt][nt][r];
            }
}

// ---------------- K2b: Sred = sum over kz slices  (grid 826 x 256, f32x4/thread)
__global__ __launch_bounds__(256) void k_reduce1(const float* __restrict__ Spart,
        float* __restrict__ Sred, int nks) {
    const int idx = blockIdx.x * 256 + threadIdx.x;   // < 211456
    const size_t e = (size_t)idx * 4;
    f32x4 s = {0.f, 0.f, 0.f, 0.f};
    for (int kz = 0; kz < nks; ++kz)
        s += *(const f32x4*)(Spart + (size_t)kz * SELEM + e);
    *(f32x4*)(Sred + e) = s;
}

// ---------------- K3: per-query argmax/top2, invq, coef, refine-list
__global__ __launch_bounds__(256) void k_argmax(const float* __restrict__ S,
        const float* __restrict__ nq2, int* __restrict__ label, float* __restrict__ coef,
        float* __restrict__ invq, int* __restrict__ rcnt, int* __restrict__ rlist) {
    const int j = blockIdx.x * 256 + threadIdx.x;
    if (j >= NQUERY) return;
    const float* row = S + (size_t)j * NPAD;
    float m1 = -1e30f, m2 = -1e30f;
    int i1 = 0, i2 = 0;
    for (int c = 0; c < NCLS; ++c) {
        float v = row[c];
        if (v > m1) { m2 = m1; i2 = i1; m1 = v; i1 = c; }
        else if (v > m2) { m2 = v; i2 = c; }
    }
    const float inv = 1.f / fmaxf(sqrtf(nq2[j]), EPSF);
    invq[j] = inv;
    label[j] = i1;
    coef[j] = expf(m1 * inv);
    if ((m1 - m2) * inv < 1e-4f) {
        int p = atomicAdd(rcnt, 1);
        if (p < RCAP) rlist[p] = j | (i1 << 13) | (i2 << 20);
    }
}

// ---------------- K4: fp64 refinement of borderline argmax decisions (1 wave/block)
__global__ __launch_bounds__(64) void k_refine(const float* __restrict__ x,
        const float* __restrict__ S, const float* __restrict__ invq,
        int* __restrict__ label, float* __restrict__ coef,
        const int* __restrict__ rcnt, const int* __restrict__ rlist) {
    const int cnt = min(*rcnt, RCAP);
    const int lane = threadIdx.x;
    for (int e = blockIdx.x; e < cnt; e += gridDim.x) {
        const int pk = rlist[e];
        const int j = pk & 8191, c1 = (pk >> 13) & 127, c2 = (pk >> 20) & 127;
        const float* xq = x + (size_t)xrow_of_query(j) * DIM;
        const int cc[2] = {c1, c2};
        double cosv[2];
#pragma unroll
        for (int s = 0; s < 2; ++s) {
            const float* xb = x + (size_t)(cc[s] * RPC) * DIM;
            double dt = 0.0, pp = 0.0, q2 = 0.0;
            for (int i = lane; i < DIM; i += 64) {
                double p = (double)xb[i] + (double)xb[i + DIM] + (double)xb[i + 2*DIM]
                         + (double)xb[i + 3*DIM] + (double)xb[i + 4*DIM];
                double qv = (double)xq[i];
                dt += p * qv; pp += p * p; q2 += qv * qv;
            }
            for (int o = 32; o; o >>= 1) {
                dt += __shfl_down(dt, o);
                pp += __shfl_down(pp, o);
                q2 += __shfl_down(q2, o);
            }
            cosv[s] = dt / (sqrt(pp) * sqrt(q2));   // /5 on proto cancels in cosine
        }
        if (lane == 0) {
            int win = (cosv[1] > cosv[0] || (cosv[1] == cosv[0] && c2 < c1)) ? c2 : c1;
            if (win != c1) {
                label[j] = win;
                coef[j] = expf(S[(size_t)j * NPAD + win] * invq[j]);
            }
        }
    }
}

// ---------------- K5: build per-class query lists
__global__ __launch_bounds__(256) void k_lists(const int* __restrict__ label,
        int* __restrict__ cls_cnt, int* __restrict__ cls_list) {
    const int j = blockIdx.x * 256 + threadIdx.x;
    if (j >= NQUERY) return;
    const int c = label[j];
    const int p = atomicAdd(&cls_cnt[c], 1);
    if (p < CAPQ) cls_list[c * CAPQ + p] = j;
}

// ---------------- K6: adapted-proto partial scatter sum, plain stores (grid 8 x NCLS x 4)
__global__ __launch_bounds__(128) void k_adapt(const float* __restrict__ x,
        const float* __restrict__ coef, const int* __restrict__ cls_cnt,
        const int* __restrict__ cls_list, float* __restrict__ APpart) {
    const int cx = blockIdx.x, c = blockIdx.y, sl = blockIdx.z;
    const int i0 = cx * 512 + threadIdx.x * 4;
    const int n = min(cls_cnt[c], CAPQ);
    f32x4 acc = {0.f, 0.f, 0.f, 0.f};
    for (int e = sl; e < n; e += 4) {
        const int j = cls_list[c * CAPQ + e];
        const float cf = coef[j];
        const f32x4 v = *(const f32x4*)(x + (size_t)xrow_of_query(j) * DIM + i0);
        acc += v * cf;
    }
    *(f32x4*)(APpart + (size_t)sl * NCLS * DIM + (size_t)c * DIM + i0) = acc;
}

// ---------------- K7a: combine slices + es*proto -> APpart slice0, partial norm2b
__global__ __launch_bounds__(256) void k_ap1(float* __restrict__ APpart,
        const float* __restrict__ proto, const float* __restrict__ es,
        float* __restrict__ norm2b) {
    const int c = blockIdx.x, ch = blockIdx.y, t = threadIdx.x;
    const int i = ch * 1024 + t * 4;
    const float e = es[c];
    f32x4 s = {0.f, 0.f, 0.f, 0.f};
#pragma unroll
    for (int sl = 0; sl < 4; ++sl)
        s += *(const f32x4*)(APpart + (size_t)sl * NCLS * DIM + (size_t)c * DIM + i);
    f32x4 pr = *(const f32x4*)(proto + (size_t)c*DIM + i);
    s += pr * e;
    *(f32x4*)(APpart + (size_t)c*DIM + i) = s;   // combined -> slice 0
    float ssq = s[0]*s[0] + s[1]*s[1] + s[2]*s[2] + s[3]*s[3];
    for (int o = 32; o; o >>= 1) ssq += __shfl_down(ssq, o);
    if ((t & 63) == 0) atomicAdd(&norm2b[c], ssq);
}

// ---------------- K7b: normalize APpart0 -> APhi bf16 (padded rows zero)
__global__ __launch_bounds__(256) void k_ap2(const float* __restrict__ AP0,
        const float* __restrict__ norm2b, short* __restrict__ APhi) {
    const int c = blockIdx.x, ch = blockIdx.y, t = threadIdx.x;
    const int i = ch * 1024 + t * 4;
    if (c >= NCLS) {
#pragma unroll
        for (int e = 0; e < 4; ++e) APhi[(size_t)c*DIM + i + e] = 0;
        return;
    }
    const float inv = 1.f / fmaxf(sqrtf(norm2b[c]), EPSF);
    f32x4 a = *(const f32x4*)(AP0 + (size_t)c*DIM + i);
#pragma unroll
    for (int e = 0; e < 4; ++e) APhi[(size_t)c*DIM + i + e] = bf16t(a[e] * inv);
}

// ---------------- K8: GEMM2 partials  Opart[kz][j,c] = q_j . apn_c  (bf16-hi only)
__global__ __launch_bounds__(256) void k_gemm2(const float* __restrict__ x,
        const short* __restrict__ APhi, float* __restrict__ Opart) {
    const int bx = blockIdx.x, kz = blockIdx.y, nks = gridDim.y;
    const int kchunk = DIM / nks, nit = kchunk / 32;
    const int w = threadIdx.x >> 6, lane = threadIdx.x & 63;
    const int lm = lane & 15, kq = lane >> 4;
    const int m0 = bx * 128 + w * 32;

    const float* pa[2];
#pragma unroll
    for (int mt = 0; mt < 2; ++mt) {
        int j = m0 + mt * 16 + lm;
        int jc = j < NQUERY ? j : NQUERY - 1;
        pa[mt] = x + (size_t)xrow_of_query(jc) * DIM + kz * kchunk + kq * 8;
    }
    const short* pb = APhi + (size_t)lm * DIM + kz * kchunk + kq * 8;

    f32x4 acc[2][7];
#pragma unroll
    for (int mt = 0; mt < 2; ++mt)
#pragma unroll
        for (int nt = 0; nt < 7; ++nt) acc[mt][nt] = (f32x4){0.f,0.f,0.f,0.f};

    for (int ks = 0; ks < nit; ++ks) {
        const int ko = ks * 32;
        bf16x8 ah[2];
#pragma unroll
        for (int mt = 0; mt < 2; ++mt) {
            f32x4 f0 = *(const f32x4*)(pa[mt] + ko);
            f32x4 f1 = *(const f32x4*)(pa[mt] + ko + 4);
            float fv[8] = {f0[0],f0[1],f0[2],f0[3],f1[0],f1[1],f1[2],f1[3]};
            bf16x8 h;
#pragma unroll
            for (int e = 0; e < 8; ++e) h[e] = bf16t(fv[e]);
            ah[mt] = h;
        }
        bf16x8 bh[7];
#pragma unroll
        for (int nt = 0; nt < 7; ++nt)
            bh[nt] = *(const bf16x8*)(pb + (size_t)nt * 16 * DIM + ko);
#pragma unroll
        for (int mt = 0; mt < 2; ++mt)
#pragma unroll
            for (int nt = 0; nt < 7; ++nt)
                acc[mt][nt] = __builtin_amdgcn_mfma_f32_16x16x32_bf16(ah[mt], bh[nt], acc[mt][nt], 0, 0, 0);
    }
    float* op = Opart + (size_t)kz * SELEM;
#pragma unroll
    for (int mt = 0; mt < 2; ++mt)
#pragma unroll
        for (int nt = 0; nt < 7; ++nt)
#pragma unroll
            for (int r = 0; r < 4; ++r) {
                int j = m0 + mt * 16 + kq * 4 + r;
                int c = nt * 16 + lm;
                op[(size_t)j * NPAD + c] = acc[mt][nt][r];
            }
}

// ---------------- K8b: out[j,c<100] = tao * invq[j] * sum_kz Opart  (grid 733 x 256)
__global__ __launch_bounds__(256) void k_reduce2(const float* __restrict__ Opart,
        const float* __restrict__ invq, const float* __restrict__ tao,
        float* __restrict__ out, int nks) {
    const int idx = blockIdx.x * 256 + threadIdx.x;   // < 187500
    if (idx >= NQUERY * 25) return;
    const int j = idx / 25, c4 = (idx % 25) * 4;
    const size_t e = (size_t)j * NPAD + c4;
    f32x4 s = {0.f, 0.f, 0.f, 0.f};
    for (int kz = 0; kz < nks; ++kz)
        s += *(const f32x4*)(Opart + (size_t)kz * SELEM + e);
    const float sc = tao[0] * invq[j];
    *(f32x4*)(out + (size_t)j * NCLS + c4) = s * sc;
}

// ---------------- workspace layout (bytes)
#define OFF_NQ2    0u
#define OFF_N2     30208u
#define OFF_N2B    30720u
#define OFF_CCNT   31232u
#define OFF_RCNT   31744u
#define ZERO_BYTES 32768u
#define OFF_SRED   32768u       // 3,383,296
#define OFF_APPART 3416064u     // 4 x 1,638,400
#define OFF_PROTO  9969664u     // 1,638,400
#define OFF_PHI    11608064u    // 917,504
#define OFF_PLO    12525568u    // 917,504
#define OFF_APHI   13443072u    // 917,504
#define OFF_LABEL  14360576u
#define OFF_COEF   14390784u
#define OFF_INVQ   14420992u
#define OFF_RLIST  14451200u
#define OFF_CLIST  14459392u
#define OFF_ES     14561792u
#define OFF_PART   14562304u    // + nks x 3,383,296 (runtime-sized)

extern "C" void kernel_launch(void* const* d_in, const int* in_sizes, int n_in,
                              void* d_out, int out_size, void* d_ws, size_t ws_size,
                              hipStream_t stream) {
    const float* x   = (const float*)d_in[0];
    const float* tao = (const float*)d_in[1];
    char* ws = (char*)d_ws;

    float* nq2     = (float*)(ws + OFF_NQ2);
    float* norm2   = (float*)(ws + OFF_N2);
    float* norm2b  = (float*)(ws + OFF_N2B);
    int*   ccnt    = (int*)  (ws + OFF_CCNT);
    int*   rcnt    = (int*)  (ws + OFF_RCNT);
    float* Sred    = (float*)(ws + OFF_SRED);
    float* APpart  = (float*)(ws + OFF_APPART);
    float* proto   = (float*)(ws + OFF_PROTO);
    short* Phi     = (short*)(ws + OFF_PHI);
    short* Plo     = (short*)(ws + OFF_PLO);
    short* APhi    = (short*)(ws + OFF_APHI);
    int*   label   = (int*)  (ws + OFF_LABEL);
    float* coef    = (float*)(ws + OFF_COEF);
    float* invq    = (float*)(ws + OFF_INVQ);
    int*   rlist   = (int*)  (ws + OFF_RLIST);
    int*   clist   = (int*)  (ws + OFF_CLIST);
    float* es      = (float*)(ws + OFF_ES);
    float* Part    = (float*)(ws + OFF_PART);

    // runtime k-split count from available scratch (pow2, 1..16)
    int nks = 1;
    if (ws_size > (size_t)OFF_PART + SLICE_BYTES) {
        size_t avail = (ws_size - OFF_PART) / SLICE_BYTES;
        nks = avail >= 16 ? 16 : (int)avail;
        while (nks & (nks - 1)) nks &= nks - 1;   // round down to power of two
    }

    hipMemsetAsync(ws, 0, ZERO_BYTES, stream);

    k_proto1 <<<dim3(NCLS, 4), 256, 0, stream>>>(x, proto, norm2);
    k_proto2 <<<dim3(NPAD, 4), 256, 0, stream>>>(proto, norm2, Phi, Plo, es);
    k_gemm1  <<<dim3(59, nks), 256, 0, stream>>>(x, Phi, Plo, Part, nq2);
    k_reduce1<<<826, 256, 0, stream>>>(Part, Sred, nks);
    k_argmax <<<30, 256, 0, stream>>>(Sred, nq2, label, coef, invq, rcnt, rlist);
    k_refine <<<512, 64, 0, stream>>>(x, Sred, invq, label, coef, rcnt, rlist);
    k_lists  <<<30, 256, 0, stream>>>(label, ccnt, clist);
    k_adapt  <<<dim3(8, NCLS, 4), 128, 0, stream>>>(x, coef, ccnt, clist, APpart);
    k_ap1    <<<dim3(NCLS, 4), 256, 0, stream>>>(APpart, proto, es, norm2b);
    k_ap2    <<<dim3(NPAD, 4), 256, 0, stream>>>(APpart, norm2b, APhi);
    k_gemm2  <<<dim3(59, nks), 256, 0, stream>>>(x, APhi, Part);
    k_reduce2<<<733, 256, 0, stream>>>(Part, invq, tao, (float*)d_out, nks);
}